// Round 1
// baseline (706.310 us; speedup 1.0000x reference)
//
#include <hip/hip_runtime.h>
#include <hip/hip_bf16.h>
#include <cstdint>

// ---- constants ----
// B=1, S=4096, HID=2048, NH=16, NKV=4, HD=128, BLK=128, LOCAL=4, GLOB=4, STRIDE=8
#define NEGV   (-1000000000.0f)
#define SCALE  0.08838834764831845f   // 128^-0.5

typedef __bf16 bf16x8 __attribute__((ext_vector_type(8)));
typedef float  f32x4  __attribute__((ext_vector_type(4)));
typedef unsigned short u16;

#define MFMA16(a, b, c) __builtin_amdgcn_mfma_f32_16x16x32_bf16((a), (b), (c), 0, 0, 0)

__device__ __forceinline__ u16 f2bf(float f) {
  union { float f; uint32_t u; } v; v.f = f;
  uint32_t u = v.u;
  u += 0x7FFFu + ((u >> 16) & 1u);   // round-to-nearest-even
  return (u16)(u >> 16);
}

// ============================================================================
// Kernel 1: QKV projection (bf16 MFMA, fp32 acc) + fused RoPE.
//   X[4096][2048] fp32 @ {Wq,Wk,Wv} fp32 -> Qr[4096][2048], Kr[4096][512] bf16
//   (roped), Vt[4][128][4096] bf16 (transposed for attention B-frag loads).
// grid (32, 24): by<16 -> Q, 16..19 -> K, 20..23 -> V. 256 threads = 4 waves.
// ============================================================================
__global__ __launch_bounds__(256, 2)
void qkv_rope_kernel(const float* __restrict__ X,
                     const float* __restrict__ Wq,
                     const float* __restrict__ Wk,
                     const float* __restrict__ Wv,
                     const float* __restrict__ cosp,
                     const float* __restrict__ sinp,
                     u16* __restrict__ Qr,
                     u16* __restrict__ Kr,
                     u16* __restrict__ Vt)
{
  const int bm = blockIdx.x;
  const int bn = blockIdx.y;
  const int tid = threadIdx.x;
  const int wave = tid >> 6;
  const int lane = tid & 63;
  const int lq  = lane >> 4;
  const int l16 = lane & 15;
  const int m0 = bm * 128;

  const float* W; int ldw, ncol0, seg;
  if (bn < 16)      { W = Wq; ldw = 2048; ncol0 = bn * 128;        seg = 0; }
  else if (bn < 20) { W = Wk; ldw = 512;  ncol0 = (bn - 16) * 128; seg = 1; }
  else              { W = Wv; ldw = 512;  ncol0 = (bn - 20) * 128; seg = 2; }

  // +8 u16 pad per row: 80B stride -> 2-way bank aliasing (free), 16B aligned
  __shared__ __align__(16) u16 As[128][40];
  __shared__ __align__(16) u16 Bs[128][40];   // [n][k] (transposed)

  f32x4 acc[2][8];
  #pragma unroll
  for (int i = 0; i < 2; ++i)
    #pragma unroll
    for (int j = 0; j < 8; ++j)
      #pragma unroll
      for (int r = 0; r < 4; ++r) acc[i][j][r] = 0.0f;

  for (int k0 = 0; k0 < 2048; k0 += 32) {
    __syncthreads();
    {  // stage A: X[m0..+128)[k0..+32) fp32 -> bf16
      const int tr = tid >> 3, tc = tid & 7;
      #pragma unroll
      for (int i = 0; i < 4; ++i) {
        const int r = tr + 32 * i;
        const float4 xv = *reinterpret_cast<const float4*>(
            X + (size_t)(m0 + r) * 2048 + k0 + tc * 4);
        u16* dst = &As[r][tc * 4];
        dst[0] = f2bf(xv.x); dst[1] = f2bf(xv.y);
        dst[2] = f2bf(xv.z); dst[3] = f2bf(xv.w);
      }
      // stage B transposed: W[k0+k][ncol0+n] -> Bs[n][k]
      #pragma unroll
      for (int i = 0; i < 4; ++i) {
        const int cid = tid + 256 * i;          // 0..1023
        const int k = cid >> 5, nq = cid & 31;  // k 0..31, n/4 0..31
        const float4 wv = *reinterpret_cast<const float4*>(
            W + (size_t)(k0 + k) * ldw + ncol0 + nq * 4);
        Bs[nq * 4 + 0][k] = f2bf(wv.x);
        Bs[nq * 4 + 1][k] = f2bf(wv.y);
        Bs[nq * 4 + 2][k] = f2bf(wv.z);
        Bs[nq * 4 + 3][k] = f2bf(wv.w);
      }
    }
    __syncthreads();
    bf16x8 af[2];
    #pragma unroll
    for (int mt = 0; mt < 2; ++mt)
      af[mt] = *reinterpret_cast<const bf16x8*>(&As[wave * 32 + mt * 16 + l16][lq * 8]);
    #pragma unroll
    for (int nt = 0; nt < 8; ++nt) {
      const bf16x8 bfr = *reinterpret_cast<const bf16x8*>(&Bs[nt * 16 + l16][lq * 8]);
      #pragma unroll
      for (int mt = 0; mt < 2; ++mt)
        acc[mt][nt] = MFMA16(af[mt], bfr, acc[mt][nt]);
    }
  }

  // epilogue — C/D layout: row = lq*4+reg, col = l16 (m89-verified)
  if (seg == 2) {       // V: no rope, store transposed Vt[kvh][d][s]
    const int kvh = ncol0 >> 7;
    #pragma unroll
    for (int mt = 0; mt < 2; ++mt) {
      const int rb = m0 + wave * 32 + mt * 16 + lq * 4;
      #pragma unroll
      for (int nt = 0; nt < 8; ++nt) {
        const int d = nt * 16 + l16;
        #pragma unroll
        for (int r = 0; r < 4; ++r)
          Vt[((size_t)kvh * 128 + d) * 4096 + rb + r] = f2bf(acc[mt][nt][r]);
      }
    }
  } else {              // Q or K: rope. 128-col tile == one head; pair (d, d+64)
    u16* dst = (seg == 0) ? Qr : Kr;
    const int ldd = (seg == 0) ? 2048 : 512;
    #pragma unroll
    for (int mt = 0; mt < 2; ++mt) {
      const int rb = m0 + wave * 32 + mt * 16 + lq * 4;
      #pragma unroll
      for (int nt = 0; nt < 4; ++nt) {
        const int d1 = nt * 16 + l16, d2 = d1 + 64;
        #pragma unroll
        for (int r = 0; r < 4; ++r) {
          const int s = rb + r;
          const float c1 = cosp[s * 128 + d1], sn1 = sinp[s * 128 + d1];
          const float c2 = cosp[s * 128 + d2], sn2 = sinp[s * 128 + d2];
          const float v1 = acc[mt][nt][r], v2 = acc[mt][nt + 4][r];
          dst[(size_t)s * ldd + ncol0 + d1] = f2bf(v1 * c1 - v2 * sn1);
          dst[(size_t)s * ldd + ncol0 + d2] = f2bf(v2 * c2 + v1 * sn2);
        }
      }
    }
  }
}

// ============================================================================
// Kernel 2: block-sparse attention, flash-style online softmax.
// grid (32 qblocks, 16 heads), 256 threads = 4 waves; wave w owns q-rows
// [w*32, w*32+32). LDS: bufK (K tile, then reused for P), bufV (V^T tile),
// both 128x128 bf16 with XOR-chunk swizzle (16B chunks, conflict-free).
// ============================================================================
__global__ __launch_bounds__(256, 2)
void attn_kernel(const u16* __restrict__ Qr,    // [4096][2048]
                 const u16* __restrict__ Kr,    // [4096][512]
                 const u16* __restrict__ Vt,    // [4][128][4096]
                 const float* __restrict__ amask, // [4096]
                 u16* __restrict__ AO)          // [4096][2048]
{
  const int n   = blockIdx.x;   // q block
  const int h   = blockIdx.y;   // head
  const int kvh = h >> 2;       // rep = 4
  const int tid = threadIdx.x;
  const int wave = tid >> 6;
  const int lane = tid & 63;
  const int lq  = lane >> 4;
  const int l16 = lane & 15;

  __shared__ __align__(16) u16 bufK[128 * 128];  // K tile; later P (per-wave 32x128)
  __shared__ __align__(16) u16 bufV[128 * 128];  // V^T tile [d][t]

  // preload Q A-fragments: A[m=l16][k=quad*8+j]
  bf16x8 qf[2][4];
  #pragma unroll
  for (int mt = 0; mt < 2; ++mt) {
    const int s = n * 128 + wave * 32 + mt * 16 + l16;
    #pragma unroll
    for (int kk = 0; kk < 4; ++kk)
      qf[mt][kk] = *reinterpret_cast<const bf16x8*>(
          Qr + (size_t)s * 2048 + h * 128 + kk * 32 + lq * 8);
  }

  f32x4 O[2][8];
  #pragma unroll
  for (int i = 0; i < 2; ++i)
    #pragma unroll
    for (int j = 0; j < 8; ++j)
      #pragma unroll
      for (int r = 0; r < 4; ++r) O[i][j][r] = 0.0f;
  float mrow[2][4], lrow[2][4];
  #pragma unroll
  for (int i = 0; i < 2; ++i)
    #pragma unroll
    for (int r = 0; r < 4; ++r) { mrow[i][r] = -3.0e38f; lrow[i][r] = 0.0f; }

  // global block indices + dup validity (reference semantics)
  int gidx[4]; bool gval[4];
  gidx[0] = 0;
  gidx[1] = (n - 24 > 0) ? n - 24 : 0;
  gidx[2] = (n - 16 > 0) ? n - 16 : 0;
  gidx[3] = (n - 8  > 0) ? n - 8  : 0;
  gval[0] = true;
  gval[1] = (gidx[1] != gidx[0]);
  gval[2] = (gidx[2] != gidx[1]);
  gval[3] = (gidx[3] != gidx[2]);

  for (int kb = 0; kb < 8; ++kb) {
    int bkey; bool bvalid; bool intra;
    if (kb < 4) { bkey = n - 3 + kb; bvalid = (bkey >= 0); intra = (kb == 3); }
    else        { bkey = gidx[kb - 4]; bvalid = gval[kb - 4]; intra = false; }
    const int bload = bvalid ? bkey : 0;

    __syncthreads();  // previous iter's P/V reads done before restaging
    // stage K (rows t, cols d) and V^T (rows d, cols t); XOR-swizzled chunks
    #pragma unroll
    for (int i = 0; i < 8; ++i) {
      const int cid = tid + 256 * i;        // 0..2047
      const int row = cid >> 4, ch = cid & 15;
      const uint4 kv = *reinterpret_cast<const uint4*>(
          Kr + ((size_t)(bload * 128 + row)) * 512 + kvh * 128 + ch * 8);
      *reinterpret_cast<uint4*>(bufK + row * 128 + ((ch ^ (row & 7)) * 8)) = kv;
      const uint4 vv = *reinterpret_cast<const uint4*>(
          Vt + ((size_t)kvh * 128 + row) * 4096 + bload * 128 + ch * 8);
      *reinterpret_cast<uint4*>(bufV + row * 128 + ((ch ^ (row & 7)) * 8)) = vv;
    }
    __syncthreads();

    // S = Q K^T : B-frag lane -> B[k=d][n=t] = K[t][d], row t = nt*16+l16
    f32x4 sacc[2][8];
    #pragma unroll
    for (int i = 0; i < 2; ++i)
      #pragma unroll
      for (int j = 0; j < 8; ++j)
        #pragma unroll
        for (int r = 0; r < 4; ++r) sacc[i][j][r] = 0.0f;
    #pragma unroll
    for (int kk = 0; kk < 4; ++kk) {
      #pragma unroll
      for (int nt = 0; nt < 8; ++nt) {
        const int row = nt * 16 + l16;
        const int ch  = kk * 4 + lq;
        const bf16x8 bfr = *reinterpret_cast<const bf16x8*>(
            bufK + row * 128 + ((ch ^ (row & 7)) * 8));
        #pragma unroll
        for (int mt = 0; mt < 2; ++mt)
          sacc[mt][nt] = MFMA16(qf[mt][kk], bfr, sacc[mt][nt]);
      }
    }

    // per-column mask value
    float kmv[8];
    #pragma unroll
    for (int nt = 0; nt < 8; ++nt)
      kmv[nt] = bvalid ? amask[bload * 128 + nt * 16 + l16] : 0.0f;

    __syncthreads();  // all waves done reading K before P overwrites bufK

    // masking + online softmax + P write (wave's own 32x128 region of bufK)
    #pragma unroll
    for (int mt = 0; mt < 2; ++mt) {
      #pragma unroll
      for (int r = 0; r < 4; ++r) {
        const int tq = wave * 32 + mt * 16 + lq * 4 + r;  // in-block q row
        float sv[8];
        float rmax = -3.0e38f;
        #pragma unroll
        for (int nt = 0; nt < 8; ++nt) {
          float s = sacc[mt][nt][r] * SCALE + (1.0f - kmv[nt]) * NEGV;
          const int tk = nt * 16 + l16;
          if (intra && tk > tq) s += NEGV;
          sv[nt] = s;
          rmax = fmaxf(rmax, s);
        }
        #pragma unroll
        for (int off = 1; off < 16; off <<= 1)
          rmax = fmaxf(rmax, __shfl_xor(rmax, off, 64));
        const float mold = mrow[mt][r];
        const float mnew = fmaxf(mold, rmax);
        const float alpha = __expf(mold - mnew);
        float rsum = 0.0f;
        u16 pb[8];
        #pragma unroll
        for (int nt = 0; nt < 8; ++nt) {
          const float pe = __expf(sv[nt] - mnew);
          rsum += pe;
          pb[nt] = f2bf(pe);
        }
        #pragma unroll
        for (int off = 1; off < 16; off <<= 1)
          rsum += __shfl_xor(rsum, off, 64);
        lrow[mt][r] = lrow[mt][r] * alpha + rsum;
        mrow[mt][r] = mnew;
        #pragma unroll
        for (int nt = 0; nt < 8; ++nt) O[mt][nt][r] *= alpha;
        // scatter P (bf16) into swizzled per-wave region
        const int prow = mt * 16 + lq * 4 + r;
        u16* pbase = bufK + wave * 4096 + prow * 128;
        #pragma unroll
        for (int nt = 0; nt < 8; ++nt) {
          const int col = nt * 16 + l16;
          pbase[((col >> 3) ^ (prow & 7)) * 8 + (col & 7)] = pb[nt];
        }
      }
    }

    // O += P @ V  (A-frag = own P rows; B-frag = V^T rows d)
    #pragma unroll
    for (int kk = 0; kk < 4; ++kk) {
      bf16x8 pf[2];
      #pragma unroll
      for (int mt = 0; mt < 2; ++mt) {
        const int prow = mt * 16 + l16;
        pf[mt] = *reinterpret_cast<const bf16x8*>(
            bufK + wave * 4096 + prow * 128 + (((kk * 4 + lq) ^ (prow & 7)) * 8));
      }
      #pragma unroll
      for (int nt = 0; nt < 8; ++nt) {
        const int vrow = nt * 16 + l16;        // d
        const int ch   = kk * 4 + lq;          // t chunk
        const bf16x8 vfr = *reinterpret_cast<const bf16x8*>(
            bufV + vrow * 128 + ((ch ^ (vrow & 7)) * 8));
        #pragma unroll
        for (int mt = 0; mt < 2; ++mt)
          O[mt][nt] = MFMA16(pf[mt], vfr, O[mt][nt]);
      }
    }
  }

  // finalize: O /= l, store AO[s][h*128+d] bf16
  #pragma unroll
  for (int mt = 0; mt < 2; ++mt) {
    #pragma unroll
    for (int r = 0; r < 4; ++r) {
      const float inv = 1.0f / lrow[mt][r];
      const int s = n * 128 + wave * 32 + mt * 16 + lq * 4 + r;
      #pragma unroll
      for (int nt = 0; nt < 8; ++nt) {
        const int d = nt * 16 + l16;
        AO[(size_t)s * 2048 + h * 128 + d] = f2bf(O[mt][nt][r] * inv);
      }
    }
  }
}

// ============================================================================
// Kernel 3: output projection. AO[4096][2048] bf16 @ Wo[2048][2048] fp32
//   -> Out[4096][2048] fp32. grid (32, 16).
// ============================================================================
__global__ __launch_bounds__(256, 2)
void outproj_kernel(const u16* __restrict__ AO,
                    const float* __restrict__ Wo,
                    float* __restrict__ Out)
{
  const int bm = blockIdx.x, bn = blockIdx.y;
  const int tid = threadIdx.x;
  const int wave = tid >> 6, lane = tid & 63;
  const int lq = lane >> 4, l16 = lane & 15;
  const int m0 = bm * 128, n0 = bn * 128;

  __shared__ __align__(16) u16 As[128][40];
  __shared__ __align__(16) u16 Bs[128][40];

  f32x4 acc[2][8];
  #pragma unroll
  for (int i = 0; i < 2; ++i)
    #pragma unroll
    for (int j = 0; j < 8; ++j)
      #pragma unroll
      for (int r = 0; r < 4; ++r) acc[i][j][r] = 0.0f;

  for (int k0 = 0; k0 < 2048; k0 += 32) {
    __syncthreads();
    #pragma unroll
    for (int i = 0; i < 2; ++i) {    // stage A (already bf16): 16B chunks
      const int cid = tid + 256 * i;            // 0..511
      const int r = cid >> 2, ch = cid & 3;
      const uint4 v = *reinterpret_cast<const uint4*>(
          AO + (size_t)(m0 + r) * 2048 + k0 + ch * 8);
      *reinterpret_cast<uint4*>(&As[r][ch * 8]) = v;
    }
    #pragma unroll
    for (int i = 0; i < 4; ++i) {    // stage B transposed
      const int cid = tid + 256 * i;
      const int k = cid >> 5, nq = cid & 31;
      const float4 wv = *reinterpret_cast<const float4*>(
          Wo + (size_t)(k0 + k) * 2048 + n0 + nq * 4);
      Bs[nq * 4 + 0][k] = f2bf(wv.x);
      Bs[nq * 4 + 1][k] = f2bf(wv.y);
      Bs[nq * 4 + 2][k] = f2bf(wv.z);
      Bs[nq * 4 + 3][k] = f2bf(wv.w);
    }
    __syncthreads();
    bf16x8 af[2];
    #pragma unroll
    for (int mt = 0; mt < 2; ++mt)
      af[mt] = *reinterpret_cast<const bf16x8*>(&As[wave * 32 + mt * 16 + l16][lq * 8]);
    #pragma unroll
    for (int nt = 0; nt < 8; ++nt) {
      const bf16x8 bfr = *reinterpret_cast<const bf16x8*>(&Bs[nt * 16 + l16][lq * 8]);
      #pragma unroll
      for (int mt = 0; mt < 2; ++mt)
        acc[mt][nt] = MFMA16(af[mt], bfr, acc[mt][nt]);
    }
  }

  #pragma unroll
  for (int mt = 0; mt < 2; ++mt) {
    const int rb = m0 + wave * 32 + mt * 16 + lq * 4;
    #pragma unroll
    for (int nt = 0; nt < 8; ++nt) {
      const int c = n0 + nt * 16 + l16;
      #pragma unroll
      for (int r = 0; r < 4; ++r)
        Out[(size_t)(rb + r) * 2048 + c] = acc[mt][nt][r];
    }
  }
}

// ============================================================================
extern "C" void kernel_launch(void* const* d_in, const int* in_sizes, int n_in,
                              void* d_out, int out_size, void* d_ws, size_t ws_size,
                              hipStream_t stream) {
  const float* X     = (const float*)d_in[0];  // hidden_states [1,4096,2048]
  const float* amask = (const float*)d_in[1];  // attention_mask_2d [1,4096]
  const float* cosp  = (const float*)d_in[2];  // [1,4096,128]
  const float* sinp  = (const float*)d_in[3];  // [1,4096,128]
  const float* Wq    = (const float*)d_in[4];  // [2048,2048]
  const float* Wk    = (const float*)d_in[5];  // [2048,512]
  const float* Wv    = (const float*)d_in[6];  // [2048,512]
  const float* Wo    = (const float*)d_in[7];  // [2048,2048]
  float* Out = (float*)d_out;                  // [1,4096,2048] fp32

  char* ws = (char*)d_ws;
  u16* Qr = (u16*)(ws);                                    // 16 MiB
  u16* Kr = (u16*)(ws + (size_t)16777216);                 //  4 MiB
  u16* Vt = (u16*)(ws + (size_t)16777216 + 4194304);       //  4 MiB
  u16* AO = (u16*)(ws + (size_t)16777216 + 4194304 + 4194304); // 16 MiB

  hipLaunchKernelGGL(qkv_rope_kernel, dim3(32, 24), dim3(256), 0, stream,
                     X, Wq, Wk, Wv, cosp, sinp, Qr, Kr, Vt);
  hipLaunchKernelGGL(attn_kernel, dim3(32, 16), dim3(256), 0, stream,
                     Qr, Kr, Vt, amask, AO);
  hipLaunchKernelGGL(outproj_kernel, dim3(32, 16), dim3(256), 0, stream,
                     AO, Wo, Out);
}

// Round 2
// 302.329 us; speedup vs baseline: 2.3362x; 2.3362x over previous
//
#include <hip/hip_runtime.h>
#include <hip/hip_bf16.h>
#include <cstdint>

// B=1, S=4096, HID=2048, NH=16, NKV=4, HD=128, BLK=128, LOCAL=4, GLOB=4, STRIDE=8
#define NEGV   (-1000000000.0f)
#define SCALE  0.08838834764831845f   // 128^-0.5

typedef __bf16 bf16x8 __attribute__((ext_vector_type(8)));
typedef float  f32x4  __attribute__((ext_vector_type(4)));
typedef unsigned short u16;
typedef unsigned int   u32;

#define MFMA16(a, b, c) __builtin_amdgcn_mfma_f32_16x16x32_bf16((a), (b), (c), 0, 0, 0)

// ---- workspace layout (u16 units). AOp aliases Xp (X dead after qkv GEMM).
#define WS_XP    ((size_t)0)          // X frag-order        [32][64] tiles, 16 MiB
#define WS_AOP   ((size_t)0)          // attn out frag-order [32][64] tiles (alias)
#define WS_WQP   ((size_t)8388608)    // Wq^T frag-order     [16][64], 8 MiB
#define WS_WKP   ((size_t)12582912)   // Wk^T frag-order     [4][64],  2 MiB
#define WS_WVP   ((size_t)13631488)   // Wv^T frag-order     [4][64],  2 MiB
#define WS_WOP   ((size_t)14680064)   // Wo^T frag-order     [16][64], 8 MiB
#define WS_QF    ((size_t)18874368)   // Q attn-A-frag order [h][4096x128], 16 MiB
#define WS_KF    ((size_t)27262976)   // K attn-B-frag order [kvh][4096x128], 4 MiB
#define WS_VF    ((size_t)29360128)   // V attn-PV-frag order[kvh][128x4096], 4 MiB
// total 60 MiB

__device__ __forceinline__ u16 f2bf(float f) {
  union { float f; u32 u; } v; v.f = f;
  u32 u = v.u;
  u += 0x7FFFu + ((u >> 16) & 1u);   // RNE
  return (u16)(u >> 16);
}

// async global->LDS, 16B per lane. LDS side must be lane-linear per wave.
__device__ __forceinline__ void gl_lds16(const u16* g, u16* l) {
  __builtin_amdgcn_global_load_lds((const __attribute__((address_space(1))) u32*)g,
                                   (__attribute__((address_space(3))) u32*)l,
                                   16, 0, 0);
}

// fragment-order u16 offset within a 128(row) x 32(k) tile
__device__ __forceinline__ int fragoff(int row, int k) {
  return ((row >> 4) * 64 + ((k >> 3) & 3) * 16 + (row & 15)) * 8 + (k & 7);
}

// ============================================================================
// Kernel 0: one-time fp32 -> bf16 conversion into fragment-order layouts.
// A-mode (X): source row-major [M][K]. B-mode (W): source [K][N] -> n-major.
// 4608 blocks x 256 thr, 2 chunks of 16B per thread.
// ============================================================================
__global__ __launch_bounds__(256, 4)
void convert_kernel(const float* __restrict__ X,
                    const float* __restrict__ Wq,
                    const float* __restrict__ Wk,
                    const float* __restrict__ Wv,
                    const float* __restrict__ Wo,
                    u16* __restrict__ ws)
{
  const int t = blockIdx.x;
  const int tid = threadIdx.x;
  const float* src; u16* dst; int tt, ldn; bool amode = false;
  if (t < 2048)      { src = X;  dst = ws + WS_XP;  tt = t;        ldn = 2048; amode = true; }
  else if (t < 3072) { src = Wq; dst = ws + WS_WQP; tt = t - 2048; ldn = 2048; }
  else if (t < 3328) { src = Wk; dst = ws + WS_WKP; tt = t - 3072; ldn = 512;  }
  else if (t < 3584) { src = Wv; dst = ws + WS_WVP; tt = t - 3328; ldn = 512;  }
  else               { src = Wo; dst = ws + WS_WOP; tt = t - 3584; ldn = 2048; }
  const int rb = tt >> 6, kb = tt & 63;
  #pragma unroll
  for (int p = 0; p < 2; ++p) {
    const int c = tid + 256 * p;
    const int row = (c >> 6) * 16 + (c & 15);     // row within 128-tile
    const int k0  = ((c >> 4) & 3) * 8;           // k within 32-tile
    union { u16 h[8]; uint4 v; } pk;
    if (amode) {
      const float* s0 = src + (size_t)(rb * 128 + row) * 2048 + kb * 32 + k0;
      const float4 a0 = *reinterpret_cast<const float4*>(s0);
      const float4 a1 = *reinterpret_cast<const float4*>(s0 + 4);
      pk.h[0] = f2bf(a0.x); pk.h[1] = f2bf(a0.y); pk.h[2] = f2bf(a0.z); pk.h[3] = f2bf(a0.w);
      pk.h[4] = f2bf(a1.x); pk.h[5] = f2bf(a1.y); pk.h[6] = f2bf(a1.z); pk.h[7] = f2bf(a1.w);
    } else {
      #pragma unroll
      for (int j = 0; j < 8; ++j)
        pk.h[j] = f2bf(src[(size_t)(kb * 32 + k0 + j) * ldn + rb * 128 + row]);
    }
    *reinterpret_cast<uint4*>(dst + (size_t)tt * 4096 + c * 8) = pk.v;
  }
}

// ---- shared GEMM main loop: 128x128 tile, BK=32, K=2048, frag-order inputs,
//      global_load_lds staging (lane-linear), conflict-free ds_read_b128.
__device__ __forceinline__ void gemm_core(const u16* __restrict__ pa,
                                          const u16* __restrict__ pb,
                                          u16* As, u16* Bs,
                                          int tid, int wave, int lane,
                                          f32x4 acc[2][8])
{
  for (int it = 0; it < 64; ++it) {
    __syncthreads();
    gl_lds16(pa + tid * 8,         As + tid * 8);
    gl_lds16(pa + (tid + 256) * 8, As + (tid + 256) * 8);
    gl_lds16(pb + tid * 8,         Bs + tid * 8);
    gl_lds16(pb + (tid + 256) * 8, Bs + (tid + 256) * 8);
    pa += 4096; pb += 4096;
    __syncthreads();
    bf16x8 af0 = *reinterpret_cast<const bf16x8*>(As + (wave * 2 + 0) * 512 + lane * 8);
    bf16x8 af1 = *reinterpret_cast<const bf16x8*>(As + (wave * 2 + 1) * 512 + lane * 8);
    #pragma unroll
    for (int nt = 0; nt < 8; ++nt) {
      const bf16x8 bfr = *reinterpret_cast<const bf16x8*>(Bs + nt * 512 + lane * 8);
      acc[0][nt] = MFMA16(af0, bfr, acc[0][nt]);
      acc[1][nt] = MFMA16(af1, bfr, acc[1][nt]);
    }
  }
}

// ============================================================================
// Kernel 1: QKV GEMM + fused RoPE, outputs written in attention frag-order.
// grid (32, 24): by<16 -> Q head by; 16..19 -> K kv-head; 20..23 -> V kv-head.
// ============================================================================
__global__ __launch_bounds__(256, 2)
void qkv_kernel(const float* __restrict__ cosp,
                const float* __restrict__ sinp,
                u16* __restrict__ ws)
{
  const int mb = blockIdx.x, bn = blockIdx.y;
  const int tid = threadIdx.x;
  const int wave = tid >> 6, lane = tid & 63;
  const int lq = lane >> 4, l16 = lane & 15;

  const u16* Ab = ws + WS_XP + (size_t)mb * 64 * 4096;
  const u16* Bb; int seg, hh;
  if (bn < 16)      { Bb = ws + WS_WQP + (size_t)bn * 64 * 4096;        seg = 0; hh = bn; }
  else if (bn < 20) { Bb = ws + WS_WKP + (size_t)(bn - 16) * 64 * 4096; seg = 1; hh = bn - 16; }
  else              { Bb = ws + WS_WVP + (size_t)(bn - 20) * 64 * 4096; seg = 2; hh = bn - 20; }

  __shared__ __align__(16) u16 As[4096];
  __shared__ __align__(16) u16 Bs[4096];

  f32x4 acc[2][8];
  #pragma unroll
  for (int i = 0; i < 2; ++i)
    #pragma unroll
    for (int j = 0; j < 8; ++j)
      #pragma unroll
      for (int r = 0; r < 4; ++r) acc[i][j][r] = 0.0f;

  gemm_core(Ab, Bb, As, Bs, tid, wave, lane, acc);

  const int m0 = mb * 128;
  if (seg == 2) {          // V -> Vf[kvh]: PV B-frag order (rows=d, k=t)
    u16* V = ws + WS_VF + (size_t)hh * 524288;
    #pragma unroll
    for (int mt = 0; mt < 2; ++mt)
      #pragma unroll
      for (int nt = 0; nt < 8; ++nt) {
        const int d = nt * 16 + l16;
        #pragma unroll
        for (int r = 0; r < 4; ++r) {
          const int s = m0 + wave * 32 + mt * 16 + lq * 4 + r;
          V[(s >> 5) * 4096 + fragoff(d, s & 31)] = f2bf(acc[mt][nt][r]);
        }
      }
  } else {                 // Q/K + RoPE (cos[d+64]==cos[d]) -> frag order
    u16* D = ws + ((seg == 0) ? WS_QF : WS_KF) + (size_t)hh * 524288;
    #pragma unroll
    for (int mt = 0; mt < 2; ++mt)
      #pragma unroll
      for (int r = 0; r < 4; ++r) {
        const int s = m0 + wave * 32 + mt * 16 + lq * 4 + r;
        const int sl = s & 127;
        u16* Dt = D + (size_t)(s >> 7) * 4 * 4096;
        #pragma unroll
        for (int nt = 0; nt < 4; ++nt) {
          const int d1 = nt * 16 + l16, d2 = d1 + 64;
          const float c  = cosp[s * 128 + d1];
          const float sn = sinp[s * 128 + d1];
          const float v1 = acc[mt][nt][r], v2 = acc[mt][nt + 4][r];
          Dt[(d1 >> 5) * 4096 + fragoff(sl, d1 & 31)] = f2bf(v1 * c - v2 * sn);
          Dt[(d2 >> 5) * 4096 + fragoff(sl, d2 & 31)] = f2bf(v2 * c + v1 * sn);
        }
      }
  }
}

// ============================================================================
// Kernel 2: block-sparse attention, online softmax. grid (32 qblk, 16 heads).
// K/V staged via global_load_lds from frag-order buffers (conflict-free).
// ============================================================================
__global__ __launch_bounds__(256, 2)
void attn_kernel(const float* __restrict__ amask, u16* __restrict__ ws)
{
  const int n = blockIdx.x, h = blockIdx.y;
  const int kvh = h >> 2;
  const int tid = threadIdx.x;
  const int wave = tid >> 6, lane = tid & 63;
  const int lq = lane >> 4, l16 = lane & 15;

  const u16* Kfb = ws + WS_KF + (size_t)kvh * 524288;
  const u16* Vfb = ws + WS_VF + (size_t)kvh * 524288;
  u16* AOp = ws + WS_AOP;

  __shared__ __align__(16) u16 bufK[16384];  // K tile (B-frag order); then P
  __shared__ __align__(16) u16 bufV[16384];  // V tile (PV B-frag order)

  // Q A-fragments: fully coalesced 16B loads from Qf
  const u16* Qb = ws + WS_QF + (size_t)h * 524288 + (size_t)n * 4 * 4096;
  bf16x8 qf[2][4];
  #pragma unroll
  for (int mt = 0; mt < 2; ++mt)
    #pragma unroll
    for (int kk = 0; kk < 4; ++kk)
      qf[mt][kk] = *reinterpret_cast<const bf16x8*>(
          Qb + (size_t)kk * 4096 + ((wave * 2 + mt) * 64 + lane) * 8);

  f32x4 O[2][8];
  #pragma unroll
  for (int i = 0; i < 2; ++i)
    #pragma unroll
    for (int j = 0; j < 8; ++j)
      #pragma unroll
      for (int r = 0; r < 4; ++r) O[i][j][r] = 0.0f;
  float mrow[2][4], lrow[2][4];
  #pragma unroll
  for (int i = 0; i < 2; ++i)
    #pragma unroll
    for (int r = 0; r < 4; ++r) { mrow[i][r] = -3.0e38f; lrow[i][r] = 0.0f; }

  // global block indices + dup validity (reference semantics, verified R1)
  int gidx[4]; bool gval[4];
  gidx[0] = 0;
  gidx[1] = (n - 24 > 0) ? n - 24 : 0;
  gidx[2] = (n - 16 > 0) ? n - 16 : 0;
  gidx[3] = (n - 8  > 0) ? n - 8  : 0;
  gval[0] = true;
  gval[1] = (gidx[1] != gidx[0]);
  gval[2] = (gidx[2] != gidx[1]);
  gval[3] = (gidx[3] != gidx[2]);

  for (int kb = 0; kb < 8; ++kb) {
    int bkey; bool bvalid; bool intra;
    if (kb < 4) { bkey = n - 3 + kb; bvalid = (bkey >= 0); intra = (kb == 3); }
    else        { bkey = gidx[kb - 4]; bvalid = gval[kb - 4]; intra = false; }
    const int bload = bvalid ? bkey : 0;

    const u16* Kb = Kfb + (size_t)bload * 16384;
    const u16* Vb = Vfb + (size_t)bload * 16384;
    __syncthreads();                 // prior P/V reads done before restage
    #pragma unroll
    for (int p = 0; p < 8; ++p) {
      gl_lds16(Kb + (tid + 256 * p) * 8, bufK + (tid + 256 * p) * 8);
      gl_lds16(Vb + (tid + 256 * p) * 8, bufV + (tid + 256 * p) * 8);
    }
    __syncthreads();

    // S = Q K^T
    f32x4 sacc[2][8];
    #pragma unroll
    for (int i = 0; i < 2; ++i)
      #pragma unroll
      for (int j = 0; j < 8; ++j)
        #pragma unroll
        for (int r = 0; r < 4; ++r) sacc[i][j][r] = 0.0f;
    #pragma unroll
    for (int kk = 0; kk < 4; ++kk)
      #pragma unroll
      for (int nt = 0; nt < 8; ++nt) {
        const bf16x8 bfr = *reinterpret_cast<const bf16x8*>(
            bufK + ((kk * 8 + nt) * 64 + lane) * 8);
        sacc[0][nt] = MFMA16(qf[0][kk], bfr, sacc[0][nt]);
        sacc[1][nt] = MFMA16(qf[1][kk], bfr, sacc[1][nt]);
      }

    float kmv[8];
    #pragma unroll
    for (int nt = 0; nt < 8; ++nt)
      kmv[nt] = bvalid ? amask[bload * 128 + nt * 16 + l16] : 0.0f;

    __syncthreads();                 // all waves done reading K before P write

    u16* pw = bufK + wave * 4096;    // per-wave P region, A-frag order
    #pragma unroll
    for (int mt = 0; mt < 2; ++mt)
      #pragma unroll
      for (int r = 0; r < 4; ++r) {
        const int tq = wave * 32 + mt * 16 + lq * 4 + r;
        float sv[8];
        float rmax = -3.0e38f;
        #pragma unroll
        for (int nt = 0; nt < 8; ++nt) {
          float s = sacc[mt][nt][r] * SCALE + (1.0f - kmv[nt]) * NEGV;
          const int tk = nt * 16 + l16;
          if (intra && tk > tq) s += NEGV;
          sv[nt] = s;
          rmax = fmaxf(rmax, s);
        }
        #pragma unroll
        for (int off = 1; off < 16; off <<= 1)
          rmax = fmaxf(rmax, __shfl_xor(rmax, off, 64));
        const float mold = mrow[mt][r];
        const float mnew = fmaxf(mold, rmax);
        const float alpha = __expf(mold - mnew);
        float rsum = 0.0f;
        u16 pb[8];
        #pragma unroll
        for (int nt = 0; nt < 8; ++nt) {
          const float pe = __expf(sv[nt] - mnew);
          rsum += pe;
          pb[nt] = f2bf(pe);
        }
        #pragma unroll
        for (int off = 1; off < 16; off <<= 1)
          rsum += __shfl_xor(rsum, off, 64);
        lrow[mt][r] = lrow[mt][r] * alpha + rsum;
        mrow[mt][r] = mnew;
        #pragma unroll
        for (int nt = 0; nt < 8; ++nt) O[mt][nt][r] *= alpha;
        // scatter P into A-frag order: elem(prow=mt*16+lq*4+r, k=nt*16+l16)
        const int l8 = l16 >> 3;
        #pragma unroll
        for (int nt = 0; nt < 8; ++nt) {
          const int lqp = (nt * 2 + l8) & 3;
          pw[(nt >> 1) * 1024 + ((mt * 4 + lqp) * 16 + lq * 4 + r) * 8 + (l16 & 7)] = pb[nt];
        }
      }

    // O += P @ V (own-wave P region; no barrier needed)
    #pragma unroll
    for (int kk = 0; kk < 4; ++kk) {
      const bf16x8 pf0 = *reinterpret_cast<const bf16x8*>(pw + kk * 1024 + lane * 8);
      const bf16x8 pf1 = *reinterpret_cast<const bf16x8*>(pw + kk * 1024 + (64 + lane) * 8);
      #pragma unroll
      for (int nt = 0; nt < 8; ++nt) {
        const bf16x8 vfr = *reinterpret_cast<const bf16x8*>(
            bufV + ((kk * 8 + nt) * 64 + lane) * 8);
        O[0][nt] = MFMA16(pf0, vfr, O[0][nt]);
        O[1][nt] = MFMA16(pf1, vfr, O[1][nt]);
      }
    }
  }

  // finalize: write AO in outproj A-frag order
  #pragma unroll
  for (int mt = 0; mt < 2; ++mt)
    #pragma unroll
    for (int r = 0; r < 4; ++r) {
      const float inv = 1.0f / lrow[mt][r];
      const int s = n * 128 + wave * 32 + mt * 16 + lq * 4 + r;
      #pragma unroll
      for (int nt = 0; nt < 8; ++nt) {
        const int kcol = h * 128 + nt * 16 + l16;
        AOp[((size_t)(s >> 7) * 64 + (kcol >> 5)) * 4096 + fragoff(s & 127, kcol & 31)] =
            f2bf(O[mt][nt][r] * inv);
      }
    }
}

// ============================================================================
// Kernel 3: output projection. AOp fragorder @ Wop fragorder -> Out fp32.
// ============================================================================
__global__ __launch_bounds__(256, 2)
void outproj_kernel(const u16* __restrict__ ws, float* __restrict__ Out)
{
  const int mb = blockIdx.x, bn = blockIdx.y;
  const int tid = threadIdx.x;
  const int wave = tid >> 6, lane = tid & 63;
  const int lq = lane >> 4, l16 = lane & 15;

  const u16* Ab = ws + WS_AOP + (size_t)mb * 64 * 4096;
  const u16* Bb = ws + WS_WOP + (size_t)bn * 64 * 4096;

  __shared__ __align__(16) u16 As[4096];
  __shared__ __align__(16) u16 Bs[4096];

  f32x4 acc[2][8];
  #pragma unroll
  for (int i = 0; i < 2; ++i)
    #pragma unroll
    for (int j = 0; j < 8; ++j)
      #pragma unroll
      for (int r = 0; r < 4; ++r) acc[i][j][r] = 0.0f;

  gemm_core(Ab, Bb, (u16*)As, (u16*)Bs, tid, wave, lane, acc);

  #pragma unroll
  for (int mt = 0; mt < 2; ++mt)
    #pragma unroll
    for (int nt = 0; nt < 8; ++nt) {
      const int ccol = bn * 128 + nt * 16 + l16;
      #pragma unroll
      for (int r = 0; r < 4; ++r) {
        const int s = mb * 128 + wave * 32 + mt * 16 + lq * 4 + r;
        Out[(size_t)s * 2048 + ccol] = acc[mt][nt][r];
      }
    }
}

// ============================================================================
extern "C" void kernel_launch(void* const* d_in, const int* in_sizes, int n_in,
                              void* d_out, int out_size, void* d_ws, size_t ws_size,
                              hipStream_t stream) {
  const float* X     = (const float*)d_in[0];
  const float* amask = (const float*)d_in[1];
  const float* cosp  = (const float*)d_in[2];
  const float* sinp  = (const float*)d_in[3];
  const float* Wq    = (const float*)d_in[4];
  const float* Wk    = (const float*)d_in[5];
  const float* Wv    = (const float*)d_in[6];
  const float* Wo    = (const float*)d_in[7];
  float* Out = (float*)d_out;
  u16* ws = (u16*)d_ws;

  hipLaunchKernelGGL(convert_kernel, dim3(4608), dim3(256), 0, stream,
                     X, Wq, Wk, Wv, Wo, ws);
  hipLaunchKernelGGL(qkv_kernel, dim3(32, 24), dim3(256), 0, stream,
                     cosp, sinp, ws);
  hipLaunchKernelGGL(attn_kernel, dim3(32, 16), dim3(256), 0, stream,
                     amask, ws);
  hipLaunchKernelGGL(outproj_kernel, dim3(32, 16), dim3(256), 0, stream,
                     ws, Out);
}

// Round 3
// 292.954 us; speedup vs baseline: 2.4110x; 1.0320x over previous
//
#include <hip/hip_runtime.h>
#include <hip/hip_bf16.h>
#include <cstdint>

// B=1, S=4096, HID=2048, NH=16, NKV=4, HD=128, BLK=128, LOCAL=4, GLOB=4, STRIDE=8
#define NEGV   (-1000000000.0f)
#define SCALE  0.08838834764831845f   // 128^-0.5

typedef __bf16 bf16x8 __attribute__((ext_vector_type(8)));
typedef float  f32x4  __attribute__((ext_vector_type(4)));
typedef unsigned short u16;
typedef unsigned int   u32;

#define MFMA16(a, b, c) __builtin_amdgcn_mfma_f32_16x16x32_bf16((a), (b), (c), 0, 0, 0)

// ---- workspace layout (u16 units). AOp aliases Xp (X dead after qkv GEMM).
#define WS_XP    ((size_t)0)          // X frag-order        [32][64] tiles, 16 MiB
#define WS_AOP   ((size_t)0)          // attn out frag-order (alias)
#define WS_WQP   ((size_t)8388608)    // Wq^T frag-order, 8 MiB
#define WS_WKP   ((size_t)12582912)   // Wk^T frag-order, 2 MiB
#define WS_WVP   ((size_t)13631488)   // Wv^T frag-order, 2 MiB
#define WS_WOP   ((size_t)14680064)   // Wo^T frag-order, 8 MiB
#define WS_QF    ((size_t)18874368)   // Q attn-A-frag order [h][4096x128], 16 MiB
#define WS_KF    ((size_t)27262976)   // K attn-B-frag order [kvh][4096x128], 4 MiB
#define WS_VF    ((size_t)29360128)   // V attn-PV-frag order[kvh][128x4096], 4 MiB

__device__ __forceinline__ u16 f2bf(float f) {
  union { float f; u32 u; } v; v.f = f;
  u32 u = v.u;
  u += 0x7FFFu + ((u >> 16) & 1u);   // RNE
  return (u16)(u >> 16);
}

__device__ __forceinline__ void gl_lds16(const u16* g, u16* l) {
  __builtin_amdgcn_global_load_lds((const __attribute__((address_space(1))) u32*)g,
                                   (__attribute__((address_space(3))) u32*)l,
                                   16, 0, 0);
}

// fragment-order u16 offset within a 128(row) x 32(k) tile
__device__ __forceinline__ int fragoff(int row, int k) {
  return ((row >> 4) * 64 + ((k >> 3) & 3) * 16 + (row & 15)) * 8 + (k & 7);
}

// ============================================================================
// Kernel 0: one-time fp32 -> bf16 conversion into fragment-order layouts.
// A-mode (X): row-major source, direct. B-mode (W): coalesced row reads ->
// LDS transpose -> packed 16B frag stores.
// ============================================================================
__global__ __launch_bounds__(256, 4)
void convert_kernel(const float* __restrict__ X,
                    const float* __restrict__ Wq,
                    const float* __restrict__ Wk,
                    const float* __restrict__ Wv,
                    const float* __restrict__ Wo,
                    u16* __restrict__ ws)
{
  const int t = blockIdx.x;
  const int tid = threadIdx.x;
  const float* src; u16* dst; int tt, ldn; bool amode = false;
  if (t < 2048)      { src = X;  dst = ws + WS_XP;  tt = t;        ldn = 2048; amode = true; }
  else if (t < 3072) { src = Wq; dst = ws + WS_WQP; tt = t - 2048; ldn = 2048; }
  else if (t < 3328) { src = Wk; dst = ws + WS_WKP; tt = t - 3072; ldn = 512;  }
  else if (t < 3584) { src = Wv; dst = ws + WS_WVP; tt = t - 3328; ldn = 512;  }
  else               { src = Wo; dst = ws + WS_WOP; tt = t - 3584; ldn = 2048; }
  const int rb = tt >> 6, kb = tt & 63;

  if (amode) {
    #pragma unroll
    for (int p = 0; p < 2; ++p) {
      const int c = tid + 256 * p;
      const int row = (c >> 6) * 16 + (c & 15);
      const int k0  = ((c >> 4) & 3) * 8;
      union { u16 h[8]; uint4 v; } pk;
      const float* s0 = src + (size_t)(rb * 128 + row) * 2048 + kb * 32 + k0;
      const float4 a0 = *reinterpret_cast<const float4*>(s0);
      const float4 a1 = *reinterpret_cast<const float4*>(s0 + 4);
      pk.h[0] = f2bf(a0.x); pk.h[1] = f2bf(a0.y); pk.h[2] = f2bf(a0.z); pk.h[3] = f2bf(a0.w);
      pk.h[4] = f2bf(a1.x); pk.h[5] = f2bf(a1.y); pk.h[6] = f2bf(a1.z); pk.h[7] = f2bf(a1.w);
      *reinterpret_cast<uint4*>(dst + (size_t)tt * 4096 + c * 8) = pk.v;
    }
  } else {
    __shared__ u16 Ls[32][136];   // [k][n], +8 pad
    #pragma unroll
    for (int i = 0; i < 4; ++i) {
      const int c = tid + 256 * i;            // 0..1023
      const int k = c >> 5, n4 = c & 31;
      const float4 wv = *reinterpret_cast<const float4*>(
          src + (size_t)(kb * 32 + k) * ldn + rb * 128 + n4 * 4);
      u16* d = &Ls[k][n4 * 4];
      d[0] = f2bf(wv.x); d[1] = f2bf(wv.y); d[2] = f2bf(wv.z); d[3] = f2bf(wv.w);
    }
    __syncthreads();
    #pragma unroll
    for (int p = 0; p < 2; ++p) {
      const int c = tid + 256 * p;
      const int row = (c >> 6) * 16 + (c & 15);
      const int k0  = ((c >> 4) & 3) * 8;
      union { u16 h[8]; uint4 v; } pk;
      #pragma unroll
      for (int j = 0; j < 8; ++j) pk.h[j] = Ls[k0 + j][row];
      *reinterpret_cast<uint4*>(dst + (size_t)tt * 4096 + c * 8) = pk.v;
    }
  }
}

// ---- shared GEMM main loop: 128x128 tile, BK=32, K=2048, frag-order inputs.
__device__ __forceinline__ void gemm_core(const u16* __restrict__ pa,
                                          const u16* __restrict__ pb,
                                          u16* As, u16* Bs,
                                          int tid, int wave, int lane,
                                          f32x4 acc[2][8])
{
  for (int it = 0; it < 64; ++it) {
    __syncthreads();
    gl_lds16(pa + tid * 8,         As + tid * 8);
    gl_lds16(pa + (tid + 256) * 8, As + (tid + 256) * 8);
    gl_lds16(pb + tid * 8,         Bs + tid * 8);
    gl_lds16(pb + (tid + 256) * 8, Bs + (tid + 256) * 8);
    pa += 4096; pb += 4096;
    __syncthreads();
    bf16x8 af0 = *reinterpret_cast<const bf16x8*>(As + (wave * 2 + 0) * 512 + lane * 8);
    bf16x8 af1 = *reinterpret_cast<const bf16x8*>(As + (wave * 2 + 1) * 512 + lane * 8);
    #pragma unroll
    for (int nt = 0; nt < 8; ++nt) {
      const bf16x8 bfr = *reinterpret_cast<const bf16x8*>(Bs + nt * 512 + lane * 8);
      acc[0][nt] = MFMA16(af0, bfr, acc[0][nt]);
      acc[1][nt] = MFMA16(af1, bfr, acc[1][nt]);
    }
  }
}

// ============================================================================
// Kernel 1: QKV GEMM + fused RoPE -> attention frag-order outputs.
// ============================================================================
__global__ __launch_bounds__(256, 2)
void qkv_kernel(const float* __restrict__ cosp,
                const float* __restrict__ sinp,
                u16* __restrict__ ws)
{
  const int mb = blockIdx.x, bn = blockIdx.y;
  const int tid = threadIdx.x;
  const int wave = tid >> 6, lane = tid & 63;
  const int lq = lane >> 4, l16 = lane & 15;

  const u16* Ab = ws + WS_XP + (size_t)mb * 64 * 4096;
  const u16* Bb; int seg, hh;
  if (bn < 16)      { Bb = ws + WS_WQP + (size_t)bn * 64 * 4096;        seg = 0; hh = bn; }
  else if (bn < 20) { Bb = ws + WS_WKP + (size_t)(bn - 16) * 64 * 4096; seg = 1; hh = bn - 16; }
  else              { Bb = ws + WS_WVP + (size_t)(bn - 20) * 64 * 4096; seg = 2; hh = bn - 20; }

  __shared__ __align__(16) u16 As[4096];
  __shared__ __align__(16) u16 Bs[4096];

  f32x4 acc[2][8];
  #pragma unroll
  for (int i = 0; i < 2; ++i)
    #pragma unroll
    for (int j = 0; j < 8; ++j)
      #pragma unroll
      for (int r = 0; r < 4; ++r) acc[i][j][r] = 0.0f;

  gemm_core(Ab, Bb, As, Bs, tid, wave, lane, acc);

  const int m0 = mb * 128;
  if (seg == 2) {          // V -> PV B-frag order (rows=d, k=t)
    u16* V = ws + WS_VF + (size_t)hh * 524288;
    #pragma unroll
    for (int mt = 0; mt < 2; ++mt)
      #pragma unroll
      for (int nt = 0; nt < 8; ++nt) {
        const int d = nt * 16 + l16;
        #pragma unroll
        for (int r = 0; r < 4; ++r) {
          const int s = m0 + wave * 32 + mt * 16 + lq * 4 + r;
          V[(s >> 5) * 4096 + fragoff(d, s & 31)] = f2bf(acc[mt][nt][r]);
        }
      }
  } else {                 // Q/K + RoPE (cos[d+64]==cos[d])
    u16* D = ws + ((seg == 0) ? WS_QF : WS_KF) + (size_t)hh * 524288;
    #pragma unroll
    for (int mt = 0; mt < 2; ++mt)
      #pragma unroll
      for (int r = 0; r < 4; ++r) {
        const int s = m0 + wave * 32 + mt * 16 + lq * 4 + r;
        const int sl = s & 127;
        u16* Dt = D + (size_t)(s >> 7) * 16384;
        #pragma unroll
        for (int nt = 0; nt < 4; ++nt) {
          const int d1 = nt * 16 + l16, d2 = d1 + 64;
          const float c  = cosp[s * 128 + d1];
          const float sn = sinp[s * 128 + d1];
          const float v1 = acc[mt][nt][r], v2 = acc[mt][nt + 4][r];
          Dt[(d1 >> 5) * 4096 + fragoff(sl, d1 & 31)] = f2bf(v1 * c - v2 * sn);
          Dt[(d2 >> 5) * 4096 + fragoff(sl, d2 & 31)] = f2bf(v2 * c + v1 * sn);
        }
      }
  }
}

// ============================================================================
// Kernel 2: block-sparse attention. 512 threads = 8 waves, wave owns 16 q-rows.
// Invalid key-blocks (exact-zero probability) are skipped entirely.
// ============================================================================
__global__ __launch_bounds__(512, 4)
void attn_kernel(const float* __restrict__ amask, u16* __restrict__ ws)
{
  const int n = blockIdx.x, h = blockIdx.y;
  const int kvh = h >> 2;
  const int tid = threadIdx.x;
  const int wave = tid >> 6, lane = tid & 63;
  const int lq = lane >> 4, l16 = lane & 15;

  const u16* Kfb = ws + WS_KF + (size_t)kvh * 524288;
  const u16* Vfb = ws + WS_VF + (size_t)kvh * 524288;
  u16* AOp = ws + WS_AOP;

  __shared__ __align__(16) u16 bufK[16384];  // K tile (B-frag); then P (A-frag)
  __shared__ __align__(16) u16 bufV[16384];  // V tile (PV B-frag)

  const u16* Qb = ws + WS_QF + (size_t)h * 524288 + (size_t)n * 16384;
  bf16x8 qf[4];
  #pragma unroll
  for (int kk = 0; kk < 4; ++kk)
    qf[kk] = *reinterpret_cast<const bf16x8*>(Qb + (size_t)kk * 4096 + (wave * 64 + lane) * 8);

  f32x4 O[8];
  #pragma unroll
  for (int j = 0; j < 8; ++j)
    #pragma unroll
    for (int r = 0; r < 4; ++r) O[j][r] = 0.0f;
  float mrow[4], lrow[4];
  #pragma unroll
  for (int r = 0; r < 4; ++r) { mrow[r] = -3.0e38f; lrow[r] = 0.0f; }

  // global block indices + dup validity (reference semantics, verified R1/R2)
  int gidx[4]; bool gval[4];
  gidx[0] = 0;
  gidx[1] = (n - 24 > 0) ? n - 24 : 0;
  gidx[2] = (n - 16 > 0) ? n - 16 : 0;
  gidx[3] = (n - 8  > 0) ? n - 8  : 0;
  gval[0] = true;
  gval[1] = (gidx[1] != gidx[0]);
  gval[2] = (gidx[2] != gidx[1]);
  gval[3] = (gidx[3] != gidx[2]);

  for (int kb = 0; kb < 8; ++kb) {
    int bkey; bool bvalid; bool intra;
    if (kb < 4) { bkey = n - 3 + kb; bvalid = (bkey >= 0); intra = (kb == 3); }
    else        { bkey = gidx[kb - 4]; bvalid = gval[kb - 4]; intra = false; }
    if (!bvalid) continue;   // exact: these blocks contribute 0 probability

    const u16* Kb = Kfb + (size_t)bkey * 16384;
    const u16* Vb = Vfb + (size_t)bkey * 16384;
    __syncthreads();                 // prior P/V reads done before restage
    #pragma unroll
    for (int p = 0; p < 4; ++p) {
      gl_lds16(Kb + (tid + 512 * p) * 8, bufK + (tid + 512 * p) * 8);
      gl_lds16(Vb + (tid + 512 * p) * 8, bufV + (tid + 512 * p) * 8);
    }
    __syncthreads();

    // S = Q K^T (wave's 16 q-rows x 128 keys)
    f32x4 sacc[8];
    #pragma unroll
    for (int j = 0; j < 8; ++j)
      #pragma unroll
      for (int r = 0; r < 4; ++r) sacc[j][r] = 0.0f;
    #pragma unroll
    for (int kk = 0; kk < 4; ++kk)
      #pragma unroll
      for (int nt = 0; nt < 8; ++nt) {
        const bf16x8 bfr = *reinterpret_cast<const bf16x8*>(
            bufK + ((kk * 8 + nt) * 64 + lane) * 8);
        sacc[nt] = MFMA16(qf[kk], bfr, sacc[nt]);
      }

    float kmv[8];
    #pragma unroll
    for (int nt = 0; nt < 8; ++nt)
      kmv[nt] = amask[bkey * 128 + nt * 16 + l16];

    __syncthreads();                 // all waves done reading K before P write

    u16* pw = bufK + wave * 2048;    // per-wave 16x128 P region, A-frag order
    #pragma unroll
    for (int r = 0; r < 4; ++r) {
      const int tq = wave * 16 + lq * 4 + r;
      float sv[8];
      float rmax = -3.0e38f;
      #pragma unroll
      for (int nt = 0; nt < 8; ++nt) {
        float s = sacc[nt][r] * SCALE + (1.0f - kmv[nt]) * NEGV;
        const int tk = nt * 16 + l16;
        if (intra && tk > tq) s += NEGV;
        sv[nt] = s;
        rmax = fmaxf(rmax, s);
      }
      #pragma unroll
      for (int off = 1; off < 16; off <<= 1)
        rmax = fmaxf(rmax, __shfl_xor(rmax, off, 64));
      const float mold = mrow[r];
      const float mnew = fmaxf(mold, rmax);
      const float alpha = __expf(mold - mnew);
      float rsum = 0.0f;
      u16 pb[8];
      #pragma unroll
      for (int nt = 0; nt < 8; ++nt) {
        const float pe = __expf(sv[nt] - mnew);
        rsum += pe;
        pb[nt] = f2bf(pe);
      }
      #pragma unroll
      for (int off = 1; off < 16; off <<= 1)
        rsum += __shfl_xor(rsum, off, 64);
      lrow[r] = lrow[r] * alpha + rsum;
      mrow[r] = mnew;
      #pragma unroll
      for (int nt = 0; nt < 8; ++nt) O[nt][r] *= alpha;
      // scatter P into A-frag order: elem(m=lq*4+r, k=nt*16+l16)
      #pragma unroll
      for (int nt = 0; nt < 8; ++nt)
        pw[(nt >> 1) * 512 + ((((nt & 1) * 2 + (l16 >> 3)) * 16) + lq * 4 + r) * 8 + (l16 & 7)] = pb[nt];
    }

    // O += P @ V (own-wave P region; no barrier needed)
    #pragma unroll
    for (int kk = 0; kk < 4; ++kk) {
      const bf16x8 pf = *reinterpret_cast<const bf16x8*>(pw + kk * 512 + lane * 8);
      #pragma unroll
      for (int nt = 0; nt < 8; ++nt) {
        const bf16x8 vfr = *reinterpret_cast<const bf16x8*>(
            bufV + ((kk * 8 + nt) * 64 + lane) * 8);
        O[nt] = MFMA16(pf, vfr, O[nt]);
      }
    }
  }

  // finalize: write AO in outproj A-frag order
  #pragma unroll
  for (int r = 0; r < 4; ++r) {
    const float inv = 1.0f / lrow[r];
    const int s = n * 128 + wave * 16 + lq * 4 + r;
    #pragma unroll
    for (int nt = 0; nt < 8; ++nt) {
      const int kcol = h * 128 + nt * 16 + l16;
      AOp[((size_t)(s >> 7) * 64 + (kcol >> 5)) * 4096 + fragoff(s & 127, kcol & 31)] =
          f2bf(O[nt][r] * inv);
    }
  }
}

// ============================================================================
// Kernel 3: output projection. AOp fragorder @ Wop fragorder -> Out fp32.
// ============================================================================
__global__ __launch_bounds__(256, 2)
void outproj_kernel(const u16* __restrict__ ws, float* __restrict__ Out)
{
  const int mb = blockIdx.x, bn = blockIdx.y;
  const int tid = threadIdx.x;
  const int wave = tid >> 6, lane = tid & 63;
  const int lq = lane >> 4, l16 = lane & 15;

  const u16* Ab = ws + WS_AOP + (size_t)mb * 64 * 4096;
  const u16* Bb = ws + WS_WOP + (size_t)bn * 64 * 4096;

  __shared__ __align__(16) u16 As[4096];
  __shared__ __align__(16) u16 Bs[4096];

  f32x4 acc[2][8];
  #pragma unroll
  for (int i = 0; i < 2; ++i)
    #pragma unroll
    for (int j = 0; j < 8; ++j)
      #pragma unroll
      for (int r = 0; r < 4; ++r) acc[i][j][r] = 0.0f;

  gemm_core(Ab, Bb, (u16*)As, (u16*)Bs, tid, wave, lane, acc);

  #pragma unroll
  for (int mt = 0; mt < 2; ++mt)
    #pragma unroll
    for (int nt = 0; nt < 8; ++nt) {
      const int ccol = bn * 128 + nt * 16 + l16;
      #pragma unroll
      for (int r = 0; r < 4; ++r) {
        const int s = mb * 128 + wave * 32 + mt * 16 + lq * 4 + r;
        Out[(size_t)s * 2048 + ccol] = acc[mt][nt][r];
      }
    }
}

// ============================================================================
extern "C" void kernel_launch(void* const* d_in, const int* in_sizes, int n_in,
                              void* d_out, int out_size, void* d_ws, size_t ws_size,
                              hipStream_t stream) {
  const float* X     = (const float*)d_in[0];
  const float* amask = (const float*)d_in[1];
  const float* cosp  = (const float*)d_in[2];
  const float* sinp  = (const float*)d_in[3];
  const float* Wq    = (const float*)d_in[4];
  const float* Wk    = (const float*)d_in[5];
  const float* Wv    = (const float*)d_in[6];
  const float* Wo    = (const float*)d_in[7];
  float* Out = (float*)d_out;
  u16* ws = (u16*)d_ws;

  hipLaunchKernelGGL(convert_kernel, dim3(4608), dim3(256), 0, stream,
                     X, Wq, Wk, Wv, Wo, ws);
  hipLaunchKernelGGL(qkv_kernel, dim3(32, 24), dim3(256), 0, stream,
                     cosp, sinp, ws);
  hipLaunchKernelGGL(attn_kernel, dim3(32, 16), dim3(512), 0, stream,
                     amask, ws);
  hipLaunchKernelGGL(outproj_kernel, dim3(32, 16), dim3(256), 0, stream,
                     ws, Out);
}